// Round 6
// baseline (3190.274 us; speedup 1.0000x reference)
//
#include <hip/hip_runtime.h>
#include <hip/hip_bf16.h>

// ---------------------------------------------------------------------------
// myLSTM: LSTM(B=64,T=512,D=256,H=256) + single-head attn (only t=0 query is
// consumed by the head!) + MLP head.
// Pipeline:
//   prep_x      : x fp32 -> bf16 (same layout)
//   prep_wit    : Wi fp32 [256,1024] -> bf16 transposed [1024,256]
//   xg_gemm     : xg = x@Wi + b (bf16 MFMA). Epilogue writes GATE-PACKED
//                 layout xg[(b*512+t)*1024 + unit*4 + gate] so the scan loads
//                 one 8B word per (batch,unit) = all 4 gates.
//   lstm_scan   : 4 WGs x 1024 threads. Each WG owns 16 batches x ALL 256
//                 units => the batch dim is embarrassingly parallel and there
//                 is NO inter-WG communication (rounds 1-5 showed the
//                 cross-XCD MALL round trip is a ~2.3us/step latency floor
//                 for any multi-WG handshake). Wh (512KB bf16) is split:
//                 K in [0,192) lives in VGPRs (Bfrag[4][6] = 96 regs/lane),
//                 K in [192,256) lives in LDS (1024 rows x 72-short pitch,
//                 147KB). hA (h_{t-1}, 16x256) in LDS, single buffer, two
//                 __syncthreads per step. Gates + cell state in registers.
//   attn_qu     : q0 = h0@Wq+bq ; u = Wk@(scale*q0) ; cb = scale*q0.bk
//   attn_sm     : scores = u.h[b,t]+cb -> softmax -> hbar = sum attn*h
//   head        : o0=hbar@Wv+bv ; o1=o0@Wo+bo ; z=relu(o1@W1+b1) ; out=z@W2+b2
// ---------------------------------------------------------------------------

typedef __attribute__((ext_vector_type(8))) short short8;   // 8 x bf16 (4 VGPR)
typedef __attribute__((ext_vector_type(4))) float float4v;  // MFMA acc

__device__ __forceinline__ unsigned short f2bf(float f) {  // RNE f32->bf16
  unsigned u = __builtin_bit_cast(unsigned, f);
  return (unsigned short)((u + 0x7fffu + ((u >> 16) & 1u)) >> 16);
}
__device__ __forceinline__ float bf2f(unsigned short h) {
  return __builtin_bit_cast(float, ((unsigned)h) << 16);
}
__device__ __forceinline__ float bcl(unsigned u) {  // low bf16 of dword
  return __builtin_bit_cast(float, u << 16);
}
__device__ __forceinline__ float bch(unsigned u) {  // high bf16 of dword
  return __builtin_bit_cast(float, u & 0xffff0000u);
}
__device__ __forceinline__ float sigm(float x) { return 1.f / (1.f + __expf(-x)); }
__device__ __forceinline__ float tanh_f(float x) { return 1.f - 2.f / (1.f + __expf(2.f * x)); }

// ---------------------------------------------------------------- prep kernels
__global__ void prep_x(const float* __restrict__ x, unsigned short* __restrict__ xbf) {
  size_t i = ((size_t)blockIdx.x * 256 + threadIdx.x) * 4;  // 8,388,608 elems
  float4 v = *(const float4*)&x[i];
  unsigned long long pk = (unsigned long long)f2bf(v.x)
                        | ((unsigned long long)f2bf(v.y) << 16)
                        | ((unsigned long long)f2bf(v.z) << 32)
                        | ((unsigned long long)f2bf(v.w) << 48);
  *(unsigned long long*)&xbf[i] = pk;
}

__global__ void prep_wit(const float* __restrict__ Wi, unsigned short* __restrict__ WiT) {
  size_t i = ((size_t)blockIdx.x * 256 + threadIdx.x) * 4;  // 262,144 elems
  float4 v = *(const float4*)&Wi[i];
  int k = (int)(i >> 10), n = (int)(i & 1023);
  WiT[(size_t)(n + 0) * 256 + k] = f2bf(v.x);
  WiT[(size_t)(n + 1) * 256 + k] = f2bf(v.y);
  WiT[(size_t)(n + 2) * 256 + k] = f2bf(v.z);
  WiT[(size_t)(n + 3) * 256 + k] = f2bf(v.w);
}

// ---------------------------------------------------------------- xg = x@Wi+b
#define XKP 40  // LDS k-pitch (shorts): 80B rows -> 16B-aligned b128, ~2-way banks
__global__ __launch_bounds__(256) void xg_gemm(const unsigned short* __restrict__ xbf,
                                               const unsigned short* __restrict__ WiT,
                                               const float* __restrict__ bias,
                                               unsigned short* __restrict__ xg) {
  __shared__ unsigned short As[128 * XKP];
  __shared__ unsigned short Bs[128 * XKP];
  const int tid = threadIdx.x;
  const int n0 = blockIdx.x * 128, m0 = blockIdx.y * 128;
  const int wave = tid >> 6, lane = tid & 63, quad = lane >> 4, l16 = lane & 15;
  const int wm = wave >> 1, wn = wave & 1;

  float4v acc[4][4];
#pragma unroll
  for (int i = 0; i < 4; ++i)
#pragma unroll
    for (int j = 0; j < 4; ++j) acc[i][j] = (float4v){0.f, 0.f, 0.f, 0.f};

  const int rr = tid >> 2, c8 = (tid & 3) * 8;  // staging coords (16B per thread)
  for (int k0 = 0; k0 < 256; k0 += 32) {
#pragma unroll
    for (int pp = 0; pp < 2; ++pp) {
      int r = pp * 64 + rr;
      *(uint4*)&As[r * XKP + c8] = *(const uint4*)&xbf[(size_t)(m0 + r) * 256 + k0 + c8];
      *(uint4*)&Bs[r * XKP + c8] = *(const uint4*)&WiT[(size_t)(n0 + r) * 256 + k0 + c8];
    }
    __syncthreads();
#pragma unroll
    for (int mt = 0; mt < 4; ++mt) {
      short8 af = *(const short8*)&As[(wm * 64 + mt * 16 + l16) * XKP + quad * 8];
#pragma unroll
      for (int nt = 0; nt < 4; ++nt) {
        short8 bf = *(const short8*)&Bs[(wn * 64 + nt * 16 + l16) * XKP + quad * 8];
        acc[mt][nt] = __builtin_amdgcn_mfma_f32_16x16x32_bf16(af, bf, acc[mt][nt], 0, 0, 0);
      }
    }
    __syncthreads();
  }
  // epilogue: +bias, bf16 store, GATE-PACKED layout for the scan:
  //   xg[(b*512+t)*1024 + unit*4 + gate]   (unit=col&255, gate=col>>8)
  // C layout: col=lane&15, row=quad*4+reg.
#pragma unroll
  for (int nt = 0; nt < 4; ++nt) {
    int col = n0 + wn * 64 + nt * 16 + l16;
    int gate = col >> 8, gu = col & 255;
    float bv = bias[col];
#pragma unroll
    for (int mt = 0; mt < 4; ++mt) {
#pragma unroll
      for (int r = 0; r < 4; ++r) {
        int m = m0 + wm * 64 + mt * 16 + quad * 4 + r;  // m = b*512 + t
        xg[(size_t)m * 1024 + gu * 4 + gate] = f2bf(acc[mt][nt][r] + bv);
      }
    }
  }
}

// ---------------------------------------------------------------- LSTM scan
// 4 WGs x 1024 threads (16 waves). bg = blockIdx.x: batches bg*16..+16.
// Wave w owns units w*16..w*16+16, all 4 gates (4 MFMA col-tiles).
// B operand: K<192 in VGPRs (Bfrag[gate][kt], 96 regs), K>=192 in LDS WhL.
// hA [16 batches][KP2] bf16 in LDS, single buffer, 2 barriers/step.
#define KP2 264   // hA row pitch (shorts): 528B, 16B-aligned, 2-way banks
#define WHP 72    // WhL row pitch (shorts): 144B, 16B-aligned, ~2-way banks
#define SCAN_LDS_BYTES (1024 * WHP * 2 + 16 * KP2 * 2)  // 147456 + 8448 = 155904
__global__ __launch_bounds__(1024, 1) void lstm_scan(const float* __restrict__ Wh,
                                                     const unsigned short* __restrict__ xgbuf,
                                                     unsigned short* __restrict__ hout) {
  extern __shared__ unsigned short smem[];
  unsigned short* WhL = smem;                 // [1024 rows][WHP]   K in [192,256)
  unsigned short* hA  = smem + 1024 * WHP;    // [16][KP2]          h_{t-1}
  const int tid = threadIdx.x;
  const int bg = blockIdx.x;
  const int wave = tid >> 6, lane = tid & 63, quad = lane >> 4, l16 = lane & 15;
  const int gu = wave * 16 + l16;  // this thread's unit (0..255)

  // ---- Bfrag (K<192) straight from global fp32 -> bf16 (one-time, ~2us)
  short8 Bfrag[4][6];
#pragma unroll
  for (int g = 0; g < 4; ++g)
#pragma unroll
    for (int kt = 0; kt < 6; ++kt) {
      short8 v;
#pragma unroll
      for (int j = 0; j < 8; ++j)
        v[j] = (short)f2bf(Wh[(size_t)(kt * 32 + quad * 8 + j) * 1024 + g * 256 + gu]);
      Bfrag[g][kt] = v;
    }

  // ---- WhL tail (K in [192,256)): row tid <-> col g*256 + w*16 + u
  {
    int col = ((tid >> 4) & 3) * 256 + (tid >> 6) * 16 + (tid & 15);
    for (int k2 = 0; k2 < 64; ++k2)
      WhL[tid * WHP + k2] = f2bf(Wh[(size_t)(192 + k2) * 1024 + col]);
  }
  for (int i = tid; i < 16 * KP2; i += 1024) hA[i] = 0;  // h_{-1} = 0
  __syncthreads();

  // cell state: lane owns (batch quad*4+r, unit gu), r=0..3
  float creg[4] = {0.f, 0.f, 0.f, 0.f};

  // xg: 8B word per (batch,t) = 4 gates of unit gu (gate-packed layout)
  const unsigned short* xgb =
      xgbuf + ((size_t)(bg * 16 + quad * 4) * 512) * 1024 + gu * 4;
  ushort4 xv[4];
#pragma unroll
  for (int r = 0; r < 4; ++r) xv[r] = *(const ushort4*)(xgb + (size_t)r * 524288);

  unsigned short* houtb = hout + ((size_t)(bg * 16 + quad * 4) * 512) * 256 + gu;

  for (int t = 0; t < 512; ++t) {
    // ---- MFMA: pre[b][4 gates of unit gu] = h_{t-1} @ Wh
    float4v acc[4];
#pragma unroll
    for (int g = 0; g < 4; ++g) acc[g] = (float4v){0.f, 0.f, 0.f, 0.f};
#pragma unroll
    for (int kt = 0; kt < 6; ++kt) {
      short8 af = *(const short8*)&hA[l16 * KP2 + kt * 32 + quad * 8];
#pragma unroll
      for (int g = 0; g < 4; ++g)
        acc[g] = __builtin_amdgcn_mfma_f32_16x16x32_bf16(af, Bfrag[g][kt], acc[g], 0, 0, 0);
    }
#pragma unroll
    for (int kt = 6; kt < 8; ++kt) {
      short8 af = *(const short8*)&hA[l16 * KP2 + kt * 32 + quad * 8];
#pragma unroll
      for (int g = 0; g < 4; ++g) {
        short8 bf = *(const short8*)&WhL[(wave * 64 + g * 16 + l16) * WHP +
                                         (kt - 6) * 32 + quad * 8];
        acc[g] = __builtin_amdgcn_mfma_f32_16x16x32_bf16(af, bf, acc[g], 0, 0, 0);
      }
    }

    // ---- prefetch xg(t+1), consumed next iteration
    int tn = (t < 511) ? t + 1 : t;
    ushort4 nxv[4];
#pragma unroll
    for (int r = 0; r < 4; ++r)
      nxv[r] = *(const ushort4*)(xgb + (size_t)r * 524288 + (size_t)tn * 1024);

    __syncthreads();  // all waves done reading hA(t-1)

    // ---- gates in registers; write h_t to hA + hout
#pragma unroll
    for (int r = 0; r < 4; ++r) {
      float gi = acc[0][r] + bf2f(xv[r].x);
      float gf = acc[1][r] + bf2f(xv[r].y);
      float gG = acc[2][r] + bf2f(xv[r].z);
      float go = acc[3][r] + bf2f(xv[r].w);
      float c = sigm(gf) * creg[r] + sigm(gi) * tanh_f(gG);
      creg[r] = c;
      unsigned short hbs = f2bf(sigm(go) * tanh_f(c));
      hA[(quad * 4 + r) * KP2 + gu] = hbs;
      houtb[((size_t)r * 512 + t) * 256] = hbs;
      xv[r] = nxv[r];
    }
    __syncthreads();  // hA(t) complete before next step's reads
  }
}

// ---------------------------------------------------------------- attention
__global__ __launch_bounds__(256) void attn_qu(const unsigned short* __restrict__ hout,
                                               const float* __restrict__ Wq,
                                               const float* __restrict__ bq,
                                               const float* __restrict__ Wk,
                                               const float* __restrict__ bk,
                                               float* __restrict__ us,
                                               float* __restrict__ cbuf) {
  __shared__ float h0S[256], q0S[256], red[256];
  const int b = blockIdx.x, tid = threadIdx.x;
  h0S[tid] = bf2f(hout[(size_t)b * 512 * 256 + tid]);
  __syncthreads();
  float a = 0.f;
  for (int k = 0; k < 256; ++k) a += h0S[k] * Wq[(size_t)k * 256 + tid];
  q0S[tid] = a + bq[tid];
  __syncthreads();
  red[tid] = q0S[tid] * bk[tid];
  __syncthreads();
  for (int s = 128; s > 0; s >>= 1) {
    if (tid < s) red[tid] += red[tid + s];
    __syncthreads();
  }
  if (tid == 0) cbuf[b] = 0.0625f * red[0];
  // u[d] = scale * dot(Wk row d, q0)
  float acc = 0.f;
  const float* wr = &Wk[(size_t)tid * 256];
  for (int e = 0; e < 256; e += 4) {
    float4 w = *(const float4*)&wr[e];
    acc += w.x * q0S[e] + w.y * q0S[e + 1] + w.z * q0S[e + 2] + w.w * q0S[e + 3];
  }
  us[b * 256 + tid] = 0.0625f * acc;
}

__global__ __launch_bounds__(256) void attn_sm(const unsigned short* __restrict__ hout,
                                               const float* __restrict__ us,
                                               const float* __restrict__ cbuf,
                                               float* __restrict__ hbar) {
  __shared__ float sS[512], red[256], hb4[4][256];
  const int b = blockIdx.x, tid = threadIdx.x, wave = tid >> 6, lane = tid & 63;
  const size_t hb_base = (size_t)b * 512 * 256;
  const float u0 = us[b * 256 + lane * 4 + 0], u1 = us[b * 256 + lane * 4 + 1];
  const float u2 = us[b * 256 + lane * 4 + 2], u3 = us[b * 256 + lane * 4 + 3];
  const float cbv = cbuf[b];
  for (int i = 0; i < 128; ++i) {
    int t = i * 4 + wave;
    unsigned long long hv = *(const unsigned long long*)&hout[hb_base + (size_t)t * 256 + lane * 4];
    unsigned lo = (unsigned)hv, hi = (unsigned)(hv >> 32);
    float p = u0 * bcl(lo) + u1 * bch(lo) + u2 * bcl(hi) + u3 * bch(hi);
    for (int m = 1; m < 64; m <<= 1) p += __shfl_xor(p, m, 64);
    if (lane == 0) sS[t] = p + cbv;
  }
  __syncthreads();
  red[tid] = fmaxf(sS[tid], sS[tid + 256]);
  __syncthreads();
  for (int s = 128; s > 0; s >>= 1) {
    if (tid < s) red[tid] = fmaxf(red[tid], red[tid + s]);
    __syncthreads();
  }
  float mx = red[0];
  __syncthreads();
  float e0 = __expf(sS[tid] - mx), e1 = __expf(sS[tid + 256] - mx);
  sS[tid] = e0; sS[tid + 256] = e1;
  red[tid] = e0 + e1;
  __syncthreads();
  for (int s = 128; s > 0; s >>= 1) {
    if (tid < s) red[tid] += red[tid + s];
    __syncthreads();
  }
  float inv = 1.f / red[0];
  // hbar[d] = (sum_t e[t]*h[t,d]) * inv  — per-wave partials over t
  float a0 = 0.f, a1 = 0.f, a2 = 0.f, a3 = 0.f;
  const int d0 = lane * 4;
  for (int i = 0; i < 128; ++i) {
    int t = wave * 128 + i;
    float w = sS[t];
    unsigned long long hv = *(const unsigned long long*)&hout[hb_base + (size_t)t * 256 + d0];
    unsigned lo = (unsigned)hv, hi = (unsigned)(hv >> 32);
    a0 += w * bcl(lo); a1 += w * bch(lo); a2 += w * bcl(hi); a3 += w * bch(hi);
  }
  hb4[wave][d0] = a0; hb4[wave][d0 + 1] = a1; hb4[wave][d0 + 2] = a2; hb4[wave][d0 + 3] = a3;
  __syncthreads();
  hbar[b * 256 + tid] = (hb4[0][tid] + hb4[1][tid] + hb4[2][tid] + hb4[3][tid]) * inv;
}

// ---------------------------------------------------------------- MLP head
__global__ __launch_bounds__(256) void head_k(const float* __restrict__ hbar,
                                              const float* __restrict__ Wv, const float* __restrict__ bv,
                                              const float* __restrict__ Wo, const float* __restrict__ bo,
                                              const float* __restrict__ W1, const float* __restrict__ b1,
                                              const float* __restrict__ W2, const float* __restrict__ b2,
                                              float* __restrict__ out) {
  __shared__ float hS[256], oS[256], o1S[256], zS[32];
  const int b = blockIdx.x, tid = threadIdx.x;
  hS[tid] = hbar[b * 256 + tid];
  __syncthreads();
  float a = 0.f;
  for (int k = 0; k < 256; ++k) a += hS[k] * Wv[(size_t)k * 256 + tid];
  oS[tid] = a + bv[tid];
  __syncthreads();
  a = 0.f;
  for (int k = 0; k < 256; ++k) a += oS[k] * Wo[(size_t)k * 256 + tid];
  o1S[tid] = a + bo[tid];
  __syncthreads();
  if (tid < 32) {
    a = 0.f;
    for (int k = 0; k < 256; ++k) a += o1S[k] * W1[k * 32 + tid];
    zS[tid] = fmaxf(a + b1[tid], 0.f);
  }
  __syncthreads();
  if (tid < 3) {
    a = 0.f;
    for (int j = 0; j < 32; ++j) a += zS[j] * W2[j * 3 + tid];
    out[b * 3 + tid] = a + b2[tid];
  }
}

// ---------------------------------------------------------------- launch
extern "C" void kernel_launch(void* const* d_in, const int* in_sizes, int n_in,
                              void* d_out, int out_size, void* d_ws, size_t ws_size,
                              hipStream_t stream) {
  const float* x  = (const float*)d_in[0];
  const float* Wi = (const float*)d_in[1];
  const float* Wh = (const float*)d_in[2];
  const float* bG = (const float*)d_in[3];
  const float* Wq = (const float*)d_in[4];
  const float* bq = (const float*)d_in[5];
  const float* Wk = (const float*)d_in[6];
  const float* bk = (const float*)d_in[7];
  const float* Wv = (const float*)d_in[8];
  const float* bv = (const float*)d_in[9];
  const float* Wo = (const float*)d_in[10];
  const float* bo = (const float*)d_in[11];
  const float* W1 = (const float*)d_in[12];
  const float* b1 = (const float*)d_in[13];
  const float* W2 = (const float*)d_in[14];
  const float* b2 = (const float*)d_in[15];
  float* out = (float*)d_out;
  char* ws = (char*)d_ws;

  unsigned short* xg    = (unsigned short*)(ws);              // 67,108,864 B
  unsigned short* hout  = (unsigned short*)(ws + 67108864);   // 16,777,216 B
  unsigned short* xbf   = (unsigned short*)(ws + 83886080);   // 16,777,216 B
  unsigned short* WiT   = (unsigned short*)(ws + 100663296);  //    524,288 B
  float*          us    = (float*)(ws + 101318656);           //     65,536 B
  float*          cbuf  = (float*)(ws + 101384192);           //      1,024 B
  float*          hbar  = (float*)(ws + 101385216);           //     65,536 B
  // total ~101.5 MB of workspace

  // lstm_scan uses 155,904 B of dynamic LDS (> default 64KB cap) — opt in.
  // Host-side attribute set, idempotent, graph-capture safe (not a stream op).
  (void)hipFuncSetAttribute((const void*)lstm_scan,
                            hipFuncAttributeMaxDynamicSharedMemorySize,
                            SCAN_LDS_BYTES);

  prep_x<<<dim3(8192), dim3(256), 0, stream>>>(x, xbf);
  prep_wit<<<dim3(256), dim3(256), 0, stream>>>(Wi, WiT);
  xg_gemm<<<dim3(8, 256), dim3(256), 0, stream>>>(xbf, WiT, bG, xg);
  lstm_scan<<<dim3(4), dim3(1024), SCAN_LDS_BYTES, stream>>>(Wh, xg, hout);
  attn_qu<<<dim3(64), dim3(256), 0, stream>>>(hout, Wq, bq, Wk, bk, us, cbuf);
  attn_sm<<<dim3(64), dim3(256), 0, stream>>>(hout, us, cbuf, hbar);
  head_k<<<dim3(64), dim3(256), 0, stream>>>(hbar, Wv, bv, Wo, bo, W1, b1, W2, b2, out);
}

// Round 7
// 2443.916 us; speedup vs baseline: 1.3054x; 1.3054x over previous
//
#include <hip/hip_runtime.h>
#include <hip/hip_bf16.h>

// ---------------------------------------------------------------------------
// myLSTM: LSTM(B=64,T=512,D=256,H=256) + single-head attn (only t=0 query is
// consumed by the head!) + MLP head.
// Pipeline:
//   prep_x      : x fp32 -> bf16 (same layout)
//   prep_wit    : Wi fp32 [256,1024] -> bf16 transposed [1024,256]
//   xg_gemm     : xg = x@Wi + b (bf16 MFMA). Epilogue writes GATE-PACKED
//                 layout xg[(b*512+t)*1024 + unit*4 + gate].
//   lstm_scan   : 4 WGs x 512 threads (8 waves = 2/SIMD -> 256 VGPR cap,
//                 round 6's 1024-thr/128-cap spill cliff avoided). Each WG
//                 owns 16 batches x ALL 256 units: NO inter-WG traffic.
//                 Wave w owns unit-groups {2w,2w+1} x 4 gates = 8 col-tiles.
//                 Wh split: K in [0,192) in VGPRs (Bfrag[2][4][6] = 192 regs),
//                 K in [192,256) in LDS (paired-col layout, 139.3 KB).
//                 hA double-buffered (2 x 16 x 264 shorts) -> ONE barrier per
//                 step, gates per-ugroup fully register-resident.
//   attn_qu     : q0 = h0@Wq+bq ; u = Wk@(scale*q0) ; cb = scale*q0.bk
//   attn_sm     : scores = u.h[b,t]+cb -> softmax -> hbar = sum attn*h
//   head        : o0=hbar@Wv+bv ; o1=o0@Wo+bo ; z=relu(o1@W1+b1) ; out=z@W2+b2
// hout layout is [t][b][u] (stores via one pointer + immediates in the scan).
// ---------------------------------------------------------------------------

typedef __attribute__((ext_vector_type(8))) short short8;   // 8 x bf16 (4 VGPR)
typedef __attribute__((ext_vector_type(4))) float float4v;  // MFMA acc

__device__ __forceinline__ unsigned short f2bf(float f) {  // RNE f32->bf16
  unsigned u = __builtin_bit_cast(unsigned, f);
  return (unsigned short)((u + 0x7fffu + ((u >> 16) & 1u)) >> 16);
}
__device__ __forceinline__ float bf2f(unsigned short h) {
  return __builtin_bit_cast(float, ((unsigned)h) << 16);
}
__device__ __forceinline__ float bcl(unsigned u) {  // low bf16 of dword
  return __builtin_bit_cast(float, u << 16);
}
__device__ __forceinline__ float bch(unsigned u) {  // high bf16 of dword
  return __builtin_bit_cast(float, u & 0xffff0000u);
}
__device__ __forceinline__ float sigm(float x) { return 1.f / (1.f + __expf(-x)); }
__device__ __forceinline__ float tanh_f(float x) { return 1.f - 2.f / (1.f + __expf(2.f * x)); }

// ---------------------------------------------------------------- prep kernels
__global__ void prep_x(const float* __restrict__ x, unsigned short* __restrict__ xbf) {
  size_t i = ((size_t)blockIdx.x * 256 + threadIdx.x) * 4;  // 8,388,608 elems
  float4 v = *(const float4*)&x[i];
  unsigned long long pk = (unsigned long long)f2bf(v.x)
                        | ((unsigned long long)f2bf(v.y) << 16)
                        | ((unsigned long long)f2bf(v.z) << 32)
                        | ((unsigned long long)f2bf(v.w) << 48);
  *(unsigned long long*)&xbf[i] = pk;
}

__global__ void prep_wit(const float* __restrict__ Wi, unsigned short* __restrict__ WiT) {
  size_t i = ((size_t)blockIdx.x * 256 + threadIdx.x) * 4;  // 262,144 elems
  float4 v = *(const float4*)&Wi[i];
  int k = (int)(i >> 10), n = (int)(i & 1023);
  WiT[(size_t)(n + 0) * 256 + k] = f2bf(v.x);
  WiT[(size_t)(n + 1) * 256 + k] = f2bf(v.y);
  WiT[(size_t)(n + 2) * 256 + k] = f2bf(v.z);
  WiT[(size_t)(n + 3) * 256 + k] = f2bf(v.w);
}

// ---------------------------------------------------------------- xg = x@Wi+b
#define XKP 40  // LDS k-pitch (shorts): 80B rows -> 16B-aligned b128, ~2-way banks
__global__ __launch_bounds__(256) void xg_gemm(const unsigned short* __restrict__ xbf,
                                               const unsigned short* __restrict__ WiT,
                                               const float* __restrict__ bias,
                                               unsigned short* __restrict__ xg) {
  __shared__ unsigned short As[128 * XKP];
  __shared__ unsigned short Bs[128 * XKP];
  const int tid = threadIdx.x;
  const int n0 = blockIdx.x * 128, m0 = blockIdx.y * 128;
  const int wave = tid >> 6, lane = tid & 63, quad = lane >> 4, l16 = lane & 15;
  const int wm = wave >> 1, wn = wave & 1;

  float4v acc[4][4];
#pragma unroll
  for (int i = 0; i < 4; ++i)
#pragma unroll
    for (int j = 0; j < 4; ++j) acc[i][j] = (float4v){0.f, 0.f, 0.f, 0.f};

  const int rr = tid >> 2, c8 = (tid & 3) * 8;  // staging coords (16B per thread)
  for (int k0 = 0; k0 < 256; k0 += 32) {
#pragma unroll
    for (int pp = 0; pp < 2; ++pp) {
      int r = pp * 64 + rr;
      *(uint4*)&As[r * XKP + c8] = *(const uint4*)&xbf[(size_t)(m0 + r) * 256 + k0 + c8];
      *(uint4*)&Bs[r * XKP + c8] = *(const uint4*)&WiT[(size_t)(n0 + r) * 256 + k0 + c8];
    }
    __syncthreads();
#pragma unroll
    for (int mt = 0; mt < 4; ++mt) {
      short8 af = *(const short8*)&As[(wm * 64 + mt * 16 + l16) * XKP + quad * 8];
#pragma unroll
      for (int nt = 0; nt < 4; ++nt) {
        short8 bf = *(const short8*)&Bs[(wn * 64 + nt * 16 + l16) * XKP + quad * 8];
        acc[mt][nt] = __builtin_amdgcn_mfma_f32_16x16x32_bf16(af, bf, acc[mt][nt], 0, 0, 0);
      }
    }
    __syncthreads();
  }
  // epilogue: +bias, bf16 store, GATE-PACKED layout for the scan:
  //   xg[(b*512+t)*1024 + unit*4 + gate]   (unit=col&255, gate=col>>8)
#pragma unroll
  for (int nt = 0; nt < 4; ++nt) {
    int col = n0 + wn * 64 + nt * 16 + l16;
    int gate = col >> 8, gu = col & 255;
    float bv = bias[col];
#pragma unroll
    for (int mt = 0; mt < 4; ++mt) {
#pragma unroll
      for (int r = 0; r < 4; ++r) {
        int m = m0 + wm * 64 + mt * 16 + quad * 4 + r;  // m = b*512 + t
        xg[(size_t)m * 1024 + gu * 4 + gate] = f2bf(acc[mt][nt][r] + bv);
      }
    }
  }
}

// ---------------------------------------------------------------- LSTM scan
// 4 WGs x 512 threads. bg = blockIdx.x: batches bg*16..+16, all 256 units.
// Wave w: unit-groups 2w, 2w+1 (16 units each) x 4 gates.
// Bfrag[uu][g][kt]: K rows kt*32..+32 (kt<6), col-tile (g, 2w+uu). 192 VGPRs.
// WhL (LDS): K in [192,256) for all 1024 cols, paired-col layout:
//   row r holds cols 2r, 2r+1: WhL[r*136 + (col&1)*64 + (k-192)], 272B rows.
// hA (LDS): [2 buffers][16 batches][KP2] bf16, double-buffered by t&1.
#define KP2 264   // hA row pitch (shorts): 528B, 16B-aligned
#define WHPR 136  // WhL row pitch (shorts): 272B, 16B-aligned
#define HA_OFF (512 * WHPR)
#define SCAN_LDS_BYTES ((512 * WHPR + 2 * 16 * KP2) * 2)  // 139264+16896 = 156160
__global__ __launch_bounds__(512, 2) void lstm_scan(const float* __restrict__ Wh,
                                                    const unsigned short* __restrict__ xgbuf,
                                                    unsigned short* __restrict__ hout) {
  extern __shared__ unsigned short sm[];
  unsigned short* WhL = sm;            // [512][WHPR]
  unsigned short* hA = sm + HA_OFF;    // [2][16][KP2]
  const int tid = threadIdx.x;
  const int bg = blockIdx.x;
  const int wave = tid >> 6, lane = tid & 63, quad = lane >> 4, l16 = lane & 15;

  // ---- Bfrag load via LDS transpose staging (scratch inside WhL area, 80KB)
  short8 Bfrag[2][4][6];
  for (int kc = 0; kc < 6; ++kc) {
    for (int idx = tid; idx < 32768; idx += 512) {
      int col = idx & 1023, ko = idx >> 10;  // k = kc*32+ko, coalesced fp32 read
      sm[col * 40 + ko] = f2bf(Wh[(size_t)(kc * 32 + ko) * 1024 + col]);
    }
    __syncthreads();
#pragma unroll
    for (int uu = 0; uu < 2; ++uu)
#pragma unroll
      for (int g = 0; g < 4; ++g) {
        int col = g * 256 + (wave * 2 + uu) * 16 + l16;
        Bfrag[uu][g][kc] = *(const short8*)&sm[col * 40 + quad * 8];
      }
    __syncthreads();
  }
  // ---- WhL tail fill: K in [192,256)
  for (int idx = tid; idx < 65536; idx += 512) {
    int col = idx & 1023, kk = idx >> 10;  // kk in [0,64)
    WhL[(col >> 1) * WHPR + (col & 1) * 64 + kk] =
        f2bf(Wh[(size_t)(192 + kk) * 1024 + col]);
  }
  for (int i = tid; i < 2 * 16 * KP2; i += 512) hA[i] = 0;  // h_{-1} = 0
  __syncthreads();

  float creg[2][4] = {{0.f, 0.f, 0.f, 0.f}, {0.f, 0.f, 0.f, 0.f}};

  // xg pointers: one per batch r; pair (uu) at immediate offset 64 shorts
  const int u0 = (wave * 2) * 16 + l16;  // unit of uu=0
  const unsigned short* xgp0 = xgbuf + ((size_t)(bg * 16 + quad * 4 + 0) * 512) * 1024 + u0 * 4;
  const unsigned short* xgp1 = xgbuf + ((size_t)(bg * 16 + quad * 4 + 1) * 512) * 1024 + u0 * 4;
  const unsigned short* xgp2 = xgbuf + ((size_t)(bg * 16 + quad * 4 + 2) * 512) * 1024 + u0 * 4;
  const unsigned short* xgp3 = xgbuf + ((size_t)(bg * 16 + quad * 4 + 3) * 512) * 1024 + u0 * 4;
  // hout [t][b][u]: one pointer, per-(uu,r) immediates, advance 16384/step
  unsigned short* hop = hout + (size_t)(bg * 16 + quad * 4) * 256 + u0;
  // WhL read base for uu=0/1 (short index); per-g offset g*128*WHPR added below
  const int X0 = u0, X1 = u0 + 16;
  const int wb0 = (X0 >> 1) * WHPR + (X0 & 1) * 64 + quad * 8;
  const int wb1 = (X1 >> 1) * WHPR + (X1 & 1) * 64 + quad * 8;

#pragma unroll 1
  for (int t = 0; t < 512; ++t) {
    const int p = t & 1;
    const unsigned short* hAr = hA + p * (16 * KP2);
    unsigned short* hAw = hA + (p ^ 1) * (16 * KP2);

    // prefetch xg(t) for all 8 (uu, r) pairs
    ushort4 xv[2][4];
    xv[0][0] = *(const ushort4*)xgp0; xv[1][0] = *(const ushort4*)(xgp0 + 64);
    xv[0][1] = *(const ushort4*)xgp1; xv[1][1] = *(const ushort4*)(xgp1 + 64);
    xv[0][2] = *(const ushort4*)xgp2; xv[1][2] = *(const ushort4*)(xgp2 + 64);
    xv[0][3] = *(const ushort4*)xgp3; xv[1][3] = *(const ushort4*)(xgp3 + 64);
    xgp0 += 1024; xgp1 += 1024; xgp2 += 1024; xgp3 += 1024;

#pragma unroll
    for (int uu = 0; uu < 2; ++uu) {
      float4v acc[4];
#pragma unroll
      for (int g = 0; g < 4; ++g) acc[g] = (float4v){0.f, 0.f, 0.f, 0.f};
#pragma unroll
      for (int kt = 0; kt < 6; ++kt) {
        short8 af = *(const short8*)&hAr[l16 * KP2 + kt * 32 + quad * 8];
#pragma unroll
        for (int g = 0; g < 4; ++g)
          acc[g] = __builtin_amdgcn_mfma_f32_16x16x32_bf16(af, Bfrag[uu][g][kt], acc[g], 0, 0, 0);
      }
      const int wb = uu ? wb1 : wb0;
#pragma unroll
      for (int kt = 6; kt < 8; ++kt) {
        short8 af = *(const short8*)&hAr[l16 * KP2 + kt * 32 + quad * 8];
#pragma unroll
        for (int g = 0; g < 4; ++g) {
          short8 bf = *(const short8*)&WhL[wb + g * (128 * WHPR) + (kt - 6) * 32];
          acc[g] = __builtin_amdgcn_mfma_f32_16x16x32_bf16(af, bf, acc[g], 0, 0, 0);
        }
      }
      // gates for (batch quad*4+r, unit (2w+uu)*16+l16), register-resident
      const int uoff = uu * 16;
#pragma unroll
      for (int r = 0; r < 4; ++r) {
        float gi = acc[0][r] + bf2f(xv[uu][r].x);
        float gf = acc[1][r] + bf2f(xv[uu][r].y);
        float gG = acc[2][r] + bf2f(xv[uu][r].z);
        float go = acc[3][r] + bf2f(xv[uu][r].w);
        float c = sigm(gf) * creg[uu][r] + sigm(gi) * tanh_f(gG);
        creg[uu][r] = c;
        unsigned short hbs = f2bf(sigm(go) * tanh_f(c));
        hAw[(quad * 4 + r) * KP2 + u0 + uoff] = hbs;  // next step's A operand
        hop[r * 256 + uoff] = hbs;                    // h history [t][b][u]
      }
    }
    hop += 16384;
    __syncthreads();  // hA(t) writes visible before next step's reads
  }
}

// ---------------------------------------------------------------- attention
// hout layout is [t][b][u]: element (b,t,d) at hout[t*16384 + b*256 + d]
__global__ __launch_bounds__(256) void attn_qu(const unsigned short* __restrict__ hout,
                                               const float* __restrict__ Wq,
                                               const float* __restrict__ bq,
                                               const float* __restrict__ Wk,
                                               const float* __restrict__ bk,
                                               float* __restrict__ us,
                                               float* __restrict__ cbuf) {
  __shared__ float h0S[256], q0S[256], red[256];
  const int b = blockIdx.x, tid = threadIdx.x;
  h0S[tid] = bf2f(hout[b * 256 + tid]);  // t = 0
  __syncthreads();
  float a = 0.f;
  for (int k = 0; k < 256; ++k) a += h0S[k] * Wq[(size_t)k * 256 + tid];
  q0S[tid] = a + bq[tid];
  __syncthreads();
  red[tid] = q0S[tid] * bk[tid];
  __syncthreads();
  for (int s = 128; s > 0; s >>= 1) {
    if (tid < s) red[tid] += red[tid + s];
    __syncthreads();
  }
  if (tid == 0) cbuf[b] = 0.0625f * red[0];
  // u[d] = scale * dot(Wk row d, q0)
  float acc = 0.f;
  const float* wr = &Wk[(size_t)tid * 256];
  for (int e = 0; e < 256; e += 4) {
    float4 w = *(const float4*)&wr[e];
    acc += w.x * q0S[e] + w.y * q0S[e + 1] + w.z * q0S[e + 2] + w.w * q0S[e + 3];
  }
  us[b * 256 + tid] = 0.0625f * acc;
}

__global__ __launch_bounds__(256) void attn_sm(const unsigned short* __restrict__ hout,
                                               const float* __restrict__ us,
                                               const float* __restrict__ cbuf,
                                               float* __restrict__ hbar) {
  __shared__ float sS[512], red[256], hb4[4][256];
  const int b = blockIdx.x, tid = threadIdx.x, wave = tid >> 6, lane = tid & 63;
  const size_t hb_base = (size_t)b * 256;  // [t][b][u]: + t*16384
  const float u0 = us[b * 256 + lane * 4 + 0], u1 = us[b * 256 + lane * 4 + 1];
  const float u2 = us[b * 256 + lane * 4 + 2], u3 = us[b * 256 + lane * 4 + 3];
  const float cbv = cbuf[b];
  for (int i = 0; i < 128; ++i) {
    int t = i * 4 + wave;
    unsigned long long hv =
        *(const unsigned long long*)&hout[hb_base + (size_t)t * 16384 + lane * 4];
    unsigned lo = (unsigned)hv, hi = (unsigned)(hv >> 32);
    float p = u0 * bcl(lo) + u1 * bch(lo) + u2 * bcl(hi) + u3 * bch(hi);
    for (int m = 1; m < 64; m <<= 1) p += __shfl_xor(p, m, 64);
    if (lane == 0) sS[t] = p + cbv;
  }
  __syncthreads();
  red[tid] = fmaxf(sS[tid], sS[tid + 256]);
  __syncthreads();
  for (int s = 128; s > 0; s >>= 1) {
    if (tid < s) red[tid] = fmaxf(red[tid], red[tid + s]);
    __syncthreads();
  }
  float mx = red[0];
  __syncthreads();
  float e0 = __expf(sS[tid] - mx), e1 = __expf(sS[tid + 256] - mx);
  sS[tid] = e0; sS[tid + 256] = e1;
  red[tid] = e0 + e1;
  __syncthreads();
  for (int s = 128; s > 0; s >>= 1) {
    if (tid < s) red[tid] += red[tid + s];
    __syncthreads();
  }
  float inv = 1.f / red[0];
  // hbar[d] = (sum_t e[t]*h[t,d]) * inv  — per-wave partials over t
  float a0 = 0.f, a1 = 0.f, a2 = 0.f, a3 = 0.f;
  const int d0 = lane * 4;
  for (int i = 0; i < 128; ++i) {
    int t = wave * 128 + i;
    float w = sS[t];
    unsigned long long hv =
        *(const unsigned long long*)&hout[hb_base + (size_t)t * 16384 + d0];
    unsigned lo = (unsigned)hv, hi = (unsigned)(hv >> 32);
    a0 += w * bcl(lo); a1 += w * bch(lo); a2 += w * bcl(hi); a3 += w * bch(hi);
  }
  hb4[wave][d0] = a0; hb4[wave][d0 + 1] = a1; hb4[wave][d0 + 2] = a2; hb4[wave][d0 + 3] = a3;
  __syncthreads();
  hbar[b * 256 + tid] = (hb4[0][tid] + hb4[1][tid] + hb4[2][tid] + hb4[3][tid]) * inv;
}

// ---------------------------------------------------------------- MLP head
__global__ __launch_bounds__(256) void head_k(const float* __restrict__ hbar,
                                              const float* __restrict__ Wv, const float* __restrict__ bv,
                                              const float* __restrict__ Wo, const float* __restrict__ bo,
                                              const float* __restrict__ W1, const float* __restrict__ b1,
                                              const float* __restrict__ W2, const float* __restrict__ b2,
                                              float* __restrict__ out) {
  __shared__ float hS[256], oS[256], o1S[256], zS[32];
  const int b = blockIdx.x, tid = threadIdx.x;
  hS[tid] = hbar[b * 256 + tid];
  __syncthreads();
  float a = 0.f;
  for (int k = 0; k < 256; ++k) a += hS[k] * Wv[(size_t)k * 256 + tid];
  oS[tid] = a + bv[tid];
  __syncthreads();
  a = 0.f;
  for (int k = 0; k < 256; ++k) a += oS[k] * Wo[(size_t)k * 256 + tid];
  o1S[tid] = a + bo[tid];
  __syncthreads();
  if (tid < 32) {
    a = 0.f;
    for (int k = 0; k < 256; ++k) a += o1S[k] * W1[k * 32 + tid];
    zS[tid] = fmaxf(a + b1[tid], 0.f);
  }
  __syncthreads();
  if (tid < 3) {
    a = 0.f;
    for (int j = 0; j < 32; ++j) a += zS[j] * W2[j * 3 + tid];
    out[b * 3 + tid] = a + b2[tid];
  }
}

// ---------------------------------------------------------------- launch
extern "C" void kernel_launch(void* const* d_in, const int* in_sizes, int n_in,
                              void* d_out, int out_size, void* d_ws, size_t ws_size,
                              hipStream_t stream) {
  const float* x  = (const float*)d_in[0];
  const float* Wi = (const float*)d_in[1];
  const float* Wh = (const float*)d_in[2];
  const float* bG = (const float*)d_in[3];
  const float* Wq = (const float*)d_in[4];
  const float* bq = (const float*)d_in[5];
  const float* Wk = (const float*)d_in[6];
  const float* bk = (const float*)d_in[7];
  const float* Wv = (const float*)d_in[8];
  const float* bv = (const float*)d_in[9];
  const float* Wo = (const float*)d_in[10];
  const float* bo = (const float*)d_in[11];
  const float* W1 = (const float*)d_in[12];
  const float* b1 = (const float*)d_in[13];
  const float* W2 = (const float*)d_in[14];
  const float* b2 = (const float*)d_in[15];
  float* out = (float*)d_out;
  char* ws = (char*)d_ws;

  unsigned short* xg    = (unsigned short*)(ws);              // 67,108,864 B
  unsigned short* hout  = (unsigned short*)(ws + 67108864);   // 16,777,216 B
  unsigned short* xbf   = (unsigned short*)(ws + 83886080);   // 16,777,216 B
  unsigned short* WiT   = (unsigned short*)(ws + 100663296);  //    524,288 B
  float*          us    = (float*)(ws + 101318656);           //     65,536 B
  float*          cbuf  = (float*)(ws + 101384192);           //      1,024 B
  float*          hbar  = (float*)(ws + 101385216);           //     65,536 B

  // lstm_scan uses 156,160 B of dynamic LDS (> default 64KB cap) — opt in.
  (void)hipFuncSetAttribute((const void*)lstm_scan,
                            hipFuncAttributeMaxDynamicSharedMemorySize,
                            SCAN_LDS_BYTES);

  prep_x<<<dim3(8192), dim3(256), 0, stream>>>(x, xbf);
  prep_wit<<<dim3(256), dim3(256), 0, stream>>>(Wi, WiT);
  xg_gemm<<<dim3(8, 256), dim3(256), 0, stream>>>(xbf, WiT, bG, xg);
  lstm_scan<<<dim3(4), dim3(512), SCAN_LDS_BYTES, stream>>>(Wh, xg, hout);
  attn_qu<<<dim3(64), dim3(256), 0, stream>>>(hout, Wq, bq, Wk, bk, us, cbuf);
  attn_sm<<<dim3(64), dim3(256), 0, stream>>>(hout, us, cbuf, hbar);
  head_k<<<dim3(64), dim3(256), 0, stream>>>(hbar, Wv, bv, Wo, bo, W1, b1, W2, b2, out);
}

// Round 8
// 2428.132 us; speedup vs baseline: 1.3139x; 1.0065x over previous
//
#include <hip/hip_runtime.h>
#include <hip/hip_bf16.h>

// ---------------------------------------------------------------------------
// myLSTM: LSTM(B=64,T=512,D=256,H=256) + single-head attn (only t=0 query is
// consumed by the head!) + MLP head.
// Pipeline:
//   prep_x      : x fp32 -> bf16 (same layout)
//   prep_wit    : Wi fp32 [256,1024] -> bf16 transposed [1024,256]
//   xg_gemm     : xg = x@Wi + b (bf16 MFMA). Epilogue writes GATE-PACKED
//                 layout xg[(b*512+t)*1024 + unit*4 + gate].
//   lstm_scan   : 4 WGs x 512 threads, NO inter-WG traffic (each WG owns 16
//                 batches x ALL 256 units). Wh split: K in [0,192) in VGPRs
//                 (Bfrag[2][4][6] = 192 regs/lane), K in [192,256) in LDS.
//                 ROUND 8 FIX: Bfrag staging is templated on the K-chunk
//                 (stage_chunk<KC>) so ALL Bfrag indices are compile-time
//                 constants. R6/R7 used a runtime kc loop (not unrollable
//                 across __syncthreads) -> whole array demoted to scratch ->
//                 VGPR_Count came back at half-cap (64/128) and every MFMA
//                 B-operand was a scratch reload (~4.2us/step).
//                 hA double-buffered -> ONE barrier per step.
//   attn_qu     : q0 = h0@Wq+bq ; u = Wk@(scale*q0) ; cb = scale*q0.bk
//   attn_sm     : scores = u.h[b,t]+cb -> softmax -> hbar = sum attn*h
//   head        : o0=hbar@Wv+bv ; o1=o0@Wo+bo ; z=relu(o1@W1+b1) ; out=z@W2+b2
// hout layout is [t][b][u] (stores via one pointer + immediates in the scan).
// ---------------------------------------------------------------------------

typedef __attribute__((ext_vector_type(8))) short short8;   // 8 x bf16 (4 VGPR)
typedef __attribute__((ext_vector_type(4))) float float4v;  // MFMA acc

__device__ __forceinline__ unsigned short f2bf(float f) {  // RNE f32->bf16
  unsigned u = __builtin_bit_cast(unsigned, f);
  return (unsigned short)((u + 0x7fffu + ((u >> 16) & 1u)) >> 16);
}
__device__ __forceinline__ float bf2f(unsigned short h) {
  return __builtin_bit_cast(float, ((unsigned)h) << 16);
}
__device__ __forceinline__ float bcl(unsigned u) {  // low bf16 of dword
  return __builtin_bit_cast(float, u << 16);
}
__device__ __forceinline__ float bch(unsigned u) {  // high bf16 of dword
  return __builtin_bit_cast(float, u & 0xffff0000u);
}
__device__ __forceinline__ float sigm(float x) { return 1.f / (1.f + __expf(-x)); }
__device__ __forceinline__ float tanh_f(float x) { return 1.f - 2.f / (1.f + __expf(2.f * x)); }

// ---------------------------------------------------------------- prep kernels
__global__ void prep_x(const float* __restrict__ x, unsigned short* __restrict__ xbf) {
  size_t i = ((size_t)blockIdx.x * 256 + threadIdx.x) * 4;  // 8,388,608 elems
  float4 v = *(const float4*)&x[i];
  unsigned long long pk = (unsigned long long)f2bf(v.x)
                        | ((unsigned long long)f2bf(v.y) << 16)
                        | ((unsigned long long)f2bf(v.z) << 32)
                        | ((unsigned long long)f2bf(v.w) << 48);
  *(unsigned long long*)&xbf[i] = pk;
}

__global__ void prep_wit(const float* __restrict__ Wi, unsigned short* __restrict__ WiT) {
  size_t i = ((size_t)blockIdx.x * 256 + threadIdx.x) * 4;  // 262,144 elems
  float4 v = *(const float4*)&Wi[i];
  int k = (int)(i >> 10), n = (int)(i & 1023);
  WiT[(size_t)(n + 0) * 256 + k] = f2bf(v.x);
  WiT[(size_t)(n + 1) * 256 + k] = f2bf(v.y);
  WiT[(size_t)(n + 2) * 256 + k] = f2bf(v.z);
  WiT[(size_t)(n + 3) * 256 + k] = f2bf(v.w);
}

// ---------------------------------------------------------------- xg = x@Wi+b
#define XKP 40  // LDS k-pitch (shorts): 80B rows -> 16B-aligned b128, ~2-way banks
__global__ __launch_bounds__(256) void xg_gemm(const unsigned short* __restrict__ xbf,
                                               const unsigned short* __restrict__ WiT,
                                               const float* __restrict__ bias,
                                               unsigned short* __restrict__ xg) {
  __shared__ unsigned short As[128 * XKP];
  __shared__ unsigned short Bs[128 * XKP];
  const int tid = threadIdx.x;
  const int n0 = blockIdx.x * 128, m0 = blockIdx.y * 128;
  const int wave = tid >> 6, lane = tid & 63, quad = lane >> 4, l16 = lane & 15;
  const int wm = wave >> 1, wn = wave & 1;

  float4v acc[4][4];
#pragma unroll
  for (int i = 0; i < 4; ++i)
#pragma unroll
    for (int j = 0; j < 4; ++j) acc[i][j] = (float4v){0.f, 0.f, 0.f, 0.f};

  const int rr = tid >> 2, c8 = (tid & 3) * 8;  // staging coords (16B per thread)
  for (int k0 = 0; k0 < 256; k0 += 32) {
#pragma unroll
    for (int pp = 0; pp < 2; ++pp) {
      int r = pp * 64 + rr;
      *(uint4*)&As[r * XKP + c8] = *(const uint4*)&xbf[(size_t)(m0 + r) * 256 + k0 + c8];
      *(uint4*)&Bs[r * XKP + c8] = *(const uint4*)&WiT[(size_t)(n0 + r) * 256 + k0 + c8];
    }
    __syncthreads();
#pragma unroll
    for (int mt = 0; mt < 4; ++mt) {
      short8 af = *(const short8*)&As[(wm * 64 + mt * 16 + l16) * XKP + quad * 8];
#pragma unroll
      for (int nt = 0; nt < 4; ++nt) {
        short8 bf = *(const short8*)&Bs[(wn * 64 + nt * 16 + l16) * XKP + quad * 8];
        acc[mt][nt] = __builtin_amdgcn_mfma_f32_16x16x32_bf16(af, bf, acc[mt][nt], 0, 0, 0);
      }
    }
    __syncthreads();
  }
  // epilogue: +bias, bf16 store, GATE-PACKED layout for the scan:
  //   xg[(b*512+t)*1024 + unit*4 + gate]   (unit=col&255, gate=col>>8)
#pragma unroll
  for (int nt = 0; nt < 4; ++nt) {
    int col = n0 + wn * 64 + nt * 16 + l16;
    int gate = col >> 8, gu = col & 255;
    float bv = bias[col];
#pragma unroll
    for (int mt = 0; mt < 4; ++mt) {
#pragma unroll
      for (int r = 0; r < 4; ++r) {
        int m = m0 + wm * 64 + mt * 16 + quad * 4 + r;  // m = b*512 + t
        xg[(size_t)m * 1024 + gu * 4 + gate] = f2bf(acc[mt][nt][r] + bv);
      }
    }
  }
}

// ---------------------------------------------------------------- LSTM scan
// 4 WGs x 512 threads. bg = blockIdx.x: batches bg*16..+16, all 256 units.
// Wave w: unit-groups 2w, 2w+1 (16 units each) x 4 gates.
// Bfrag[uu][g][kc]: K rows kc*32..+32 (kc<6), col-tile (g, 2w+uu). 192 VGPRs.
// WhL (LDS): K in [192,256) for all 1024 cols, paired-col layout:
//   row r holds cols 2r, 2r+1: WhL[r*136 + (col&1)*64 + (k-192)], 272B rows.
// hA (LDS): [2 buffers][16 batches][KP2] bf16, double-buffered by t&1.
#define KP2 264   // hA row pitch (shorts): 528B, 16B-aligned
#define WHPR 136  // WhL row pitch (shorts): 272B, 16B-aligned
#define HA_OFF (512 * WHPR)
#define SCAN_LDS_BYTES ((512 * WHPR + 2 * 16 * KP2) * 2)  // 139264+16896 = 156160

// Bfrag staging chunk with COMPILE-TIME chunk index KC (keeps Bfrag indices
// constant so the array stays in VGPRs — see round-8 note above).
template <int KC>
__device__ __forceinline__ void stage_chunk(const float* __restrict__ Wh,
                                            unsigned short* __restrict__ sm,
                                            int tid, int wave, int quad, int l16,
                                            short8 (&Bfrag)[2][4][6]) {
  for (int idx = tid; idx < 32768; idx += 512) {
    int col = idx & 1023, ko = idx >> 10;  // coalesced fp32 read of K-row
    sm[col * 40 + ko] = f2bf(Wh[(size_t)(KC * 32 + ko) * 1024 + col]);
  }
  __syncthreads();
#pragma unroll
  for (int uu = 0; uu < 2; ++uu)
#pragma unroll
    for (int g = 0; g < 4; ++g) {
      int col = g * 256 + (wave * 2 + uu) * 16 + l16;
      Bfrag[uu][g][KC] = *(const short8*)&sm[col * 40 + quad * 8];
    }
  __syncthreads();
}

__global__ __launch_bounds__(512, 2) void lstm_scan(const float* __restrict__ Wh,
                                                    const unsigned short* __restrict__ xgbuf,
                                                    unsigned short* __restrict__ hout) {
  extern __shared__ unsigned short sm[];
  unsigned short* WhL = sm;            // [512][WHPR]
  unsigned short* hA = sm + HA_OFF;    // [2][16][KP2]
  const int tid = threadIdx.x;
  const int bg = blockIdx.x;
  const int wave = tid >> 6, lane = tid & 63, quad = lane >> 4, l16 = lane & 15;

  // ---- Bfrag load: 6 chunks, each with compile-time index
  short8 Bfrag[2][4][6];
  stage_chunk<0>(Wh, sm, tid, wave, quad, l16, Bfrag);
  stage_chunk<1>(Wh, sm, tid, wave, quad, l16, Bfrag);
  stage_chunk<2>(Wh, sm, tid, wave, quad, l16, Bfrag);
  stage_chunk<3>(Wh, sm, tid, wave, quad, l16, Bfrag);
  stage_chunk<4>(Wh, sm, tid, wave, quad, l16, Bfrag);
  stage_chunk<5>(Wh, sm, tid, wave, quad, l16, Bfrag);

  // ---- WhL tail fill: K in [192,256)
  for (int idx = tid; idx < 65536; idx += 512) {
    int col = idx & 1023, kk = idx >> 10;  // kk in [0,64)
    WhL[(col >> 1) * WHPR + (col & 1) * 64 + kk] =
        f2bf(Wh[(size_t)(192 + kk) * 1024 + col]);
  }
  for (int i = tid; i < 2 * 16 * KP2; i += 512) hA[i] = 0;  // h_{-1} = 0
  __syncthreads();

  float creg[2][4] = {{0.f, 0.f, 0.f, 0.f}, {0.f, 0.f, 0.f, 0.f}};

  const int u0 = (wave * 2) * 16 + l16;  // unit of uu=0
  // xg base: batch (bg*16 + quad*4), unit u0, gate-packed (4 shorts per unit)
  const unsigned short* xgq =
      xgbuf + ((size_t)(bg * 16 + quad * 4) * 512) * 1024 + u0 * 4;
  // hout [t][b][u]: one pointer, per-(uu,r) immediates, advance 16384/step
  unsigned short* hop = hout + (size_t)(bg * 16 + quad * 4) * 256 + u0;
  // WhL read base for uu=0/1 (short index); per-g offset g*128*WHPR added below
  const int wb0 = (u0 >> 1) * WHPR + (u0 & 1) * 64 + quad * 8;
  const int wb1 = ((u0 + 16) >> 1) * WHPR + ((u0 + 16) & 1) * 64 + quad * 8;

#pragma unroll 1
  for (int t = 0; t < 512; ++t) {
    const int p = t & 1;
    const unsigned short* hAr = hA + p * (16 * KP2);
    unsigned short* hAw = hA + (p ^ 1) * (16 * KP2);

    // xg(t) loads for all 8 (uu, r) pairs — issued first, consumed ~300cy later
    ushort4 xv[2][4];
#pragma unroll
    for (int r = 0; r < 4; ++r) {
      const unsigned short* xq = xgq + (size_t)r * 524288;
      xv[0][r] = *(const ushort4*)xq;
      xv[1][r] = *(const ushort4*)(xq + 64);
    }
    xgq += 1024;

#pragma unroll
    for (int uu = 0; uu < 2; ++uu) {
      float4v acc[4];
#pragma unroll
      for (int g = 0; g < 4; ++g) acc[g] = (float4v){0.f, 0.f, 0.f, 0.f};
#pragma unroll
      for (int kt = 0; kt < 6; ++kt) {
        short8 af = *(const short8*)&hAr[l16 * KP2 + kt * 32 + quad * 8];
#pragma unroll
        for (int g = 0; g < 4; ++g)
          acc[g] = __builtin_amdgcn_mfma_f32_16x16x32_bf16(af, Bfrag[uu][g][kt], acc[g], 0, 0, 0);
      }
      const int wb = uu ? wb1 : wb0;
#pragma unroll
      for (int kt = 6; kt < 8; ++kt) {
        short8 af = *(const short8*)&hAr[l16 * KP2 + kt * 32 + quad * 8];
#pragma unroll
        for (int g = 0; g < 4; ++g) {
          short8 bf = *(const short8*)&WhL[wb + g * (128 * WHPR) + (kt - 6) * 32];
          acc[g] = __builtin_amdgcn_mfma_f32_16x16x32_bf16(af, bf, acc[g], 0, 0, 0);
        }
      }
      // gates for (batch quad*4+r, unit u0+uu*16), register-resident
      const int uoff = uu * 16;
#pragma unroll
      for (int r = 0; r < 4; ++r) {
        float gi = acc[0][r] + bf2f(xv[uu][r].x);
        float gf = acc[1][r] + bf2f(xv[uu][r].y);
        float gG = acc[2][r] + bf2f(xv[uu][r].z);
        float go = acc[3][r] + bf2f(xv[uu][r].w);
        float c = sigm(gf) * creg[uu][r] + sigm(gi) * tanh_f(gG);
        creg[uu][r] = c;
        unsigned short hbs = f2bf(sigm(go) * tanh_f(c));
        hAw[(quad * 4 + r) * KP2 + u0 + uoff] = hbs;  // next step's A operand
        hop[r * 256 + uoff] = hbs;                    // h history [t][b][u]
      }
    }
    hop += 16384;
    __syncthreads();  // hA(t) writes visible before next step's reads
  }
}

// ---------------------------------------------------------------- attention
// hout layout is [t][b][u]: element (b,t,d) at hout[t*16384 + b*256 + d]
__global__ __launch_bounds__(256) void attn_qu(const unsigned short* __restrict__ hout,
                                               const float* __restrict__ Wq,
                                               const float* __restrict__ bq,
                                               const float* __restrict__ Wk,
                                               const float* __restrict__ bk,
                                               float* __restrict__ us,
                                               float* __restrict__ cbuf) {
  __shared__ float h0S[256], q0S[256], red[256];
  const int b = blockIdx.x, tid = threadIdx.x;
  h0S[tid] = bf2f(hout[b * 256 + tid]);  // t = 0
  __syncthreads();
  float a = 0.f;
  for (int k = 0; k < 256; ++k) a += h0S[k] * Wq[(size_t)k * 256 + tid];
  q0S[tid] = a + bq[tid];
  __syncthreads();
  red[tid] = q0S[tid] * bk[tid];
  __syncthreads();
  for (int s = 128; s > 0; s >>= 1) {
    if (tid < s) red[tid] += red[tid + s];
    __syncthreads();
  }
  if (tid == 0) cbuf[b] = 0.0625f * red[0];
  // u[d] = scale * dot(Wk row d, q0)
  float acc = 0.f;
  const float* wr = &Wk[(size_t)tid * 256];
  for (int e = 0; e < 256; e += 4) {
    float4 w = *(const float4*)&wr[e];
    acc += w.x * q0S[e] + w.y * q0S[e + 1] + w.z * q0S[e + 2] + w.w * q0S[e + 3];
  }
  us[b * 256 + tid] = 0.0625f * acc;
}

__global__ __launch_bounds__(256) void attn_sm(const unsigned short* __restrict__ hout,
                                               const float* __restrict__ us,
                                               const float* __restrict__ cbuf,
                                               float* __restrict__ hbar) {
  __shared__ float sS[512], red[256], hb4[4][256];
  const int b = blockIdx.x, tid = threadIdx.x, wave = tid >> 6, lane = tid & 63;
  const size_t hb_base = (size_t)b * 256;  // [t][b][u]: + t*16384
  const float u0 = us[b * 256 + lane * 4 + 0], u1 = us[b * 256 + lane * 4 + 1];
  const float u2 = us[b * 256 + lane * 4 + 2], u3 = us[b * 256 + lane * 4 + 3];
  const float cbv = cbuf[b];
  for (int i = 0; i < 128; ++i) {
    int t = i * 4 + wave;
    unsigned long long hv =
        *(const unsigned long long*)&hout[hb_base + (size_t)t * 16384 + lane * 4];
    unsigned lo = (unsigned)hv, hi = (unsigned)(hv >> 32);
    float p = u0 * bcl(lo) + u1 * bch(lo) + u2 * bcl(hi) + u3 * bch(hi);
    for (int m = 1; m < 64; m <<= 1) p += __shfl_xor(p, m, 64);
    if (lane == 0) sS[t] = p + cbv;
  }
  __syncthreads();
  red[tid] = fmaxf(sS[tid], sS[tid + 256]);
  __syncthreads();
  for (int s = 128; s > 0; s >>= 1) {
    if (tid < s) red[tid] = fmaxf(red[tid], red[tid + s]);
    __syncthreads();
  }
  float mx = red[0];
  __syncthreads();
  float e0 = __expf(sS[tid] - mx), e1 = __expf(sS[tid + 256] - mx);
  sS[tid] = e0; sS[tid + 256] = e1;
  red[tid] = e0 + e1;
  __syncthreads();
  for (int s = 128; s > 0; s >>= 1) {
    if (tid < s) red[tid] += red[tid + s];
    __syncthreads();
  }
  float inv = 1.f / red[0];
  // hbar[d] = (sum_t e[t]*h[t,d]) * inv  — per-wave partials over t
  float a0 = 0.f, a1 = 0.f, a2 = 0.f, a3 = 0.f;
  const int d0 = lane * 4;
  for (int i = 0; i < 128; ++i) {
    int t = wave * 128 + i;
    float w = sS[t];
    unsigned long long hv =
        *(const unsigned long long*)&hout[hb_base + (size_t)t * 16384 + d0];
    unsigned lo = (unsigned)hv, hi = (unsigned)(hv >> 32);
    a0 += w * bcl(lo); a1 += w * bch(lo); a2 += w * bcl(hi); a3 += w * bch(hi);
  }
  hb4[wave][d0] = a0; hb4[wave][d0 + 1] = a1; hb4[wave][d0 + 2] = a2; hb4[wave][d0 + 3] = a3;
  __syncthreads();
  hbar[b * 256 + tid] = (hb4[0][tid] + hb4[1][tid] + hb4[2][tid] + hb4[3][tid]) * inv;
}

// ---------------------------------------------------------------- MLP head
__global__ __launch_bounds__(256) void head_k(const float* __restrict__ hbar,
                                              const float* __restrict__ Wv, const float* __restrict__ bv,
                                              const float* __restrict__ Wo, const float* __restrict__ bo,
                                              const float* __restrict__ W1, const float* __restrict__ b1,
                                              const float* __restrict__ W2, const float* __restrict__ b2,
                                              float* __restrict__ out) {
  __shared__ float hS[256], oS[256], o1S[256], zS[32];
  const int b = blockIdx.x, tid = threadIdx.x;
  hS[tid] = hbar[b * 256 + tid];
  __syncthreads();
  float a = 0.f;
  for (int k = 0; k < 256; ++k) a += hS[k] * Wv[(size_t)k * 256 + tid];
  oS[tid] = a + bv[tid];
  __syncthreads();
  a = 0.f;
  for (int k = 0; k < 256; ++k) a += oS[k] * Wo[(size_t)k * 256 + tid];
  o1S[tid] = a + bo[tid];
  __syncthreads();
  if (tid < 32) {
    a = 0.f;
    for (int k = 0; k < 256; ++k) a += o1S[k] * W1[k * 32 + tid];
    zS[tid] = fmaxf(a + b1[tid], 0.f);
  }
  __syncthreads();
  if (tid < 3) {
    a = 0.f;
    for (int j = 0; j < 32; ++j) a += zS[j] * W2[j * 3 + tid];
    out[b * 3 + tid] = a + b2[tid];
  }
}

// ---------------------------------------------------------------- launch
extern "C" void kernel_launch(void* const* d_in, const int* in_sizes, int n_in,
                              void* d_out, int out_size, void* d_ws, size_t ws_size,
                              hipStream_t stream) {
  const float* x  = (const float*)d_in[0];
  const float* Wi = (const float*)d_in[1];
  const float* Wh = (const float*)d_in[2];
  const float* bG = (const float*)d_in[3];
  const float* Wq = (const float*)d_in[4];
  const float* bq = (const float*)d_in[5];
  const float* Wk = (const float*)d_in[6];
  const float* bk = (const float*)d_in[7];
  const float* Wv = (const float*)d_in[8];
  const float* bv = (const float*)d_in[9];
  const float* Wo = (const float*)d_in[10];
  const float* bo = (const float*)d_in[11];
  const float* W1 = (const float*)d_in[12];
  const float* b1 = (const float*)d_in[13];
  const float* W2 = (const float*)d_in[14];
  const float* b2 = (const float*)d_in[15];
  float* out = (float*)d_out;
  char* ws = (char*)d_ws;

  unsigned short* xg    = (unsigned short*)(ws);              // 67,108,864 B
  unsigned short* hout  = (unsigned short*)(ws + 67108864);   // 16,777,216 B
  unsigned short* xbf   = (unsigned short*)(ws + 83886080);   // 16,777,216 B
  unsigned short* WiT   = (unsigned short*)(ws + 100663296);  //    524,288 B
  float*          us    = (float*)(ws + 101318656);           //     65,536 B
  float*          cbuf  = (float*)(ws + 101384192);           //      1,024 B
  float*          hbar  = (float*)(ws + 101385216);           //     65,536 B

  // lstm_scan uses 156,160 B of dynamic LDS (> default 64KB cap) — opt in.
  (void)hipFuncSetAttribute((const void*)lstm_scan,
                            hipFuncAttributeMaxDynamicSharedMemorySize,
                            SCAN_LDS_BYTES);

  prep_x<<<dim3(8192), dim3(256), 0, stream>>>(x, xbf);
  prep_wit<<<dim3(256), dim3(256), 0, stream>>>(Wi, WiT);
  xg_gemm<<<dim3(8, 256), dim3(256), 0, stream>>>(xbf, WiT, bG, xg);
  lstm_scan<<<dim3(4), dim3(512), SCAN_LDS_BYTES, stream>>>(Wh, xg, hout);
  attn_qu<<<dim3(64), dim3(256), 0, stream>>>(hout, Wq, bq, Wk, bk, us, cbuf);
  attn_sm<<<dim3(64), dim3(256), 0, stream>>>(hout, us, cbuf, hbar);
  head_k<<<dim3(64), dim3(256), 0, stream>>>(hbar, Wv, bv, Wo, bo, W1, b1, W2, b2, out);
}